// Round 7
// baseline (324.106 us; speedup 1.0000x reference)
//
#include <hip/hip_runtime.h>
#include <hip/hip_bf16.h>
#include <math.h>

// Problem constants
#define TDIM 4096
#define CDIM 256
#define BDIM 8
#define NTOK (BDIM * TDIM)   // 32768 rows
#define HIDDIM 1024
#define NCHUNK 128
#define CHLEN 32             // 4096 / 128

typedef float f32x4 __attribute__((ext_vector_type(4)));
typedef __bf16 bf16x8 __attribute__((ext_vector_type(8)));
typedef __bf16 bf16x4 __attribute__((ext_vector_type(4)));

// async global->LDS, 16 B/lane, lands at wave-uniform base + lane*16
#define GLDS16(gp, lp) __builtin_amdgcn_global_load_lds( \
    (const __attribute__((address_space(1))) void*)(gp), \
    (__attribute__((address_space(3))) void*)(lp), 16, 0, 0)

__device__ __forceinline__ float sigm(float v) { return 1.0f / (1.0f + __expf(-v)); }

// ---------------------------------------------------------------------------
// Weight pack: fp32 [K,N] -> bf16 transposed [N,K].
//   WkvrT [768][256] = [Wk^T; Wv^T; Wr^T]
//   WoT   [256][256]
//   Wkfr  [1280][256] = [Wkf^T; Wrf^T]
//   WvfT  [256][1024]
// ---------------------------------------------------------------------------
__global__ __launch_bounds__(256) void pack_weights(
    const float* __restrict__ Wk, const float* __restrict__ Wv,
    const float* __restrict__ Wr, const float* __restrict__ Wo,
    const float* __restrict__ Wkf, const float* __restrict__ Wvf,
    const float* __restrict__ Wrf,
    __bf16* __restrict__ WkvrT, __bf16* __restrict__ WoT,
    __bf16* __restrict__ Wkfr, __bf16* __restrict__ WvfT) {
  long long j = (long long)blockIdx.x * 256 + threadIdx.x;
  if (j < 196608) {
    int n = (int)(j >> 8), k = (int)(j & 255);
    const float* src = (n < 256) ? Wk : (n < 512 ? Wv : Wr);
    WkvrT[j] = (__bf16)src[k * 256 + (n & 255)];
    return;
  }
  j -= 196608;
  if (j < 65536) { int n = (int)(j >> 8), k = (int)(j & 255);
    WoT[j] = (__bf16)Wo[k * 256 + n]; return; }
  j -= 65536;
  if (j < 327680) { int n = (int)(j >> 8), k = (int)(j & 255);
    Wkfr[j] = (__bf16)(n < 1024 ? Wkf[(long long)k * 1024 + n]
                                : Wrf[k * 256 + (n - 1024)]);
    return; }
  j -= 327680;
  if (j < 262144) { int n = (int)(j >> 10), k = (int)(j & 1023);
    WvfT[j] = (__bf16)Wvf[(long long)k * 256 + n]; return; }
}

// ---------------------------------------------------------------------------
// LayerNorm over C=256: one wave per row, 4 rows/block, float4/bf16x4 loads.
// ---------------------------------------------------------------------------
template <typename T>
__global__ __launch_bounds__(256) void ln_kernel(
    const T* __restrict__ x, const float* __restrict__ gamma,
    const float* __restrict__ beta, __bf16* __restrict__ h) {
  const int wave = threadIdx.x >> 6, lane = threadIdx.x & 63;
  const long long row = (long long)blockIdx.x * 4 + wave;
  const long long base = row * CDIM + lane * 4;
  f32x4 v;
  if constexpr (sizeof(T) == 4) {
    v = *(const f32x4*)&x[base];
  } else {
    bf16x4 t = *(const bf16x4*)&x[base];
    v[0] = (float)t[0]; v[1] = (float)t[1]; v[2] = (float)t[2]; v[3] = (float)t[3];
  }
  float s = v[0] + v[1] + v[2] + v[3];
  float s2 = v[0]*v[0] + v[1]*v[1] + v[2]*v[2] + v[3]*v[3];
  #pragma unroll
  for (int o = 1; o < 64; o <<= 1) { s += __shfl_xor(s, o); s2 += __shfl_xor(s2, o); }
  const float mean = s * (1.0f / CDIM);
  const float var = s2 * (1.0f / CDIM) - mean * mean;
  const float rstd = rsqrtf(var + 1e-5f);
  const f32x4 g4 = *(const f32x4*)&gamma[lane * 4];
  const f32x4 b4 = *(const f32x4*)&beta[lane * 4];
  bf16x4 o;
  #pragma unroll
  for (int r = 0; r < 4; r++) o[r] = (__bf16)((v[r] - mean) * rstd * g4[r] + b4[r]);
  *(bf16x4*)&h[base] = o;
}

// ---------------------------------------------------------------------------
// Barrier-free-K-loop bf16 MFMA GEMM:  C[M,N] = A[M,K] * Bt[N,K]^T
// Block = 4 waves stacked in M (256 rows); wave tile 64 x 64 (BN=64).
// B panel [64][256k] staged in LDS once per 256-k chunk (XOR-swizzled 16B
// chunks -> conflict-free ds_read_b128 at 512 B row stride). A streamed
// global->VGPR per wave with an explicit 3-slot prefetch pipeline (PD=2),
// K-loop fully unrolled (K template param) so the compiler hoists loads and
// places exact per-register waitcnts. ZERO barriers in the steady state.
// Accumulator TRANSPOSED (mfma(fb,fa)): lane (quad,mrow) reg r ->
//   row = mtile+mrow, col = ntile + quad*4 + r (4 consecutive cols/lane).
// EPI 0: planar kvr store, plane = blockIdx.y>>2 (0:k 1:v 2:sigmoid->r)
// EPI 1: bf16 out = f32 src + acc                   (x1h)
// EPI 2: y<16: kk = relu(acc)^2 [stride 1024]; y>=16: g2 = sigmoid [stride 256]
// EPI 3: f32 out = (f32)srcH + (f32)gate * acc      (final)
// ---------------------------------------------------------------------------
template <int K, int EPI>
__global__ __launch_bounds__(256, 3) void gemm5(
    const __bf16* __restrict__ A, const __bf16* __restrict__ Bt,
    int M, int N,
    float* __restrict__ outF, __bf16* __restrict__ outH,
    __bf16* __restrict__ outH2,
    const float* __restrict__ srcF, const __bf16* __restrict__ srcH,
    const __bf16* __restrict__ gate) {
  constexpr int NIT = K / 32;
  __shared__ __bf16 sB[64 * 256];   // 32 KB, one 256-k chunk of B, swizzled

  const int tid = threadIdx.x;
  const int wave = tid >> 6, lane = tid & 63;
  const int quad = lane >> 4, mrow = lane & 15;
  const long long m0 = (long long)blockIdx.x * 256 + wave * 64;
  const long long bn = (long long)blockIdx.y * 64;

  // Cooperative B-chunk stage. Dest chunk j holds source k-chunk
  // (j&31)^(row&31) of row j>>5 (swizzle on source; dest stays contiguous).
  auto stageB = [&](int c) {
    #pragma unroll
    for (int i = 0; i < 8; i++) {
      const int j = i * 256 + tid;
      const int row = j >> 5;
      const int kc = ((j & 31) ^ (row & 31)) * 8;
      GLDS16(Bt + (bn + row) * (long long)K + c * 256 + kc,
             &sB[(i * 256 + wave * 64) * 8]);
    }
  };

  const __bf16* pA[4];
  #pragma unroll
  for (int mt = 0; mt < 4; mt++)
    pA[mt] = A + (m0 + mt * 16 + mrow) * (long long)K + quad * 8;

  f32x4 acc[4][4] = {};
  bf16x8 fa[3][4];   // 3-slot A prefetch pipeline (PD=2)

  stageB(0);
  __syncthreads();   // drains B stage; A pipeline starts after

  auto loadA = [&](int i, int s) {
    #pragma unroll
    for (int mt = 0; mt < 4; mt++)
      fa[s][mt] = *(const bf16x8*)(pA[mt] + (long long)i * 32);
  };
  loadA(0, 0);
  if (NIT > 1) loadA(1, 1);

  #pragma unroll
  for (int i = 0; i < NIT; i++) {
    if constexpr (K > 256) {
      if ((i & 7) == 0 && i > 0) {
        __syncthreads();          // all waves done reading previous chunk
        stageB(i >> 3);
        __syncthreads();          // chunk staged (syncthreads drains vmcnt)
      }
    }
    if (i + 2 < NIT) loadA(i + 2, (i + 2) % 3);
    const int ii = i & 7;         // k-iter within current B chunk
    bf16x8 fb[4];
    #pragma unroll
    for (int nt = 0; nt < 4; nt++) {
      const int n = nt * 16 + mrow;
      const int pos = (ii * 4 + quad) ^ (n & 31);   // de-swizzle
      fb[nt] = *(const bf16x8*)&sB[n * 256 + pos * 8];
    }
    #pragma unroll
    for (int mt = 0; mt < 4; mt++)
      #pragma unroll
      for (int nt = 0; nt < 4; nt++)
        acc[mt][nt] = __builtin_amdgcn_mfma_f32_16x16x32_bf16(fb[nt], fa[i % 3][mt], acc[mt][nt], 0, 0, 0);
  }

  #pragma unroll
  for (int mt = 0; mt < 4; mt++) {
    #pragma unroll
    for (int nt = 0; nt < 4; nt++) {
      const long long row = m0 + mt * 16 + mrow;
      const int cloc = nt * 16 + quad * 4;          // col within 64-wide tile
      const long long colb = bn + cloc;
      const f32x4 a = acc[mt][nt];
      if (EPI == 0) {
        const int plane = blockIdx.y >> 2;          // 4 y-blocks per plane
        __bf16* o = outH + (long long)plane * ((long long)M * 256);
        const long long c2 = colb & 255;
        bf16x4 v;
        if (plane == 2) {
          #pragma unroll
          for (int r = 0; r < 4; r++) v[r] = (__bf16)sigm(a[r]);
        } else {
          #pragma unroll
          for (int r = 0; r < 4; r++) v[r] = (__bf16)a[r];
        }
        *(bf16x4*)&o[row * 256 + c2] = v;
      } else if (EPI == 1) {
        const long long idx = row * N + colb;
        const f32x4 s4 = *(const f32x4*)&srcF[idx];
        bf16x4 v;
        #pragma unroll
        for (int r = 0; r < 4; r++) v[r] = (__bf16)(s4[r] + a[r]);
        *(bf16x4*)&outH[idx] = v;
      } else if (EPI == 2) {
        if (blockIdx.y < 16) {
          bf16x4 v;
          #pragma unroll
          for (int r = 0; r < 4; r++) { float t = a[r] > 0.0f ? a[r] : 0.0f; v[r] = (__bf16)(t * t); }
          *(bf16x4*)&outH[row * 1024 + colb] = v;
        } else {
          bf16x4 v;
          #pragma unroll
          for (int r = 0; r < 4; r++) v[r] = (__bf16)sigm(a[r]);
          *(bf16x4*)&outH2[row * 256 + (colb - 1024)] = v;
        }
      } else {
        const long long idx = row * N + colb;
        const bf16x4 s4 = *(const bf16x4*)&srcH[idx];
        const bf16x4 g4 = *(const bf16x4*)&gate[idx];
        f32x4 v;
        #pragma unroll
        for (int r = 0; r < 4; r++) v[r] = (float)s4[r] + (float)g4[r] * a[r];
        *(f32x4*)&outF[idx] = v;
      }
    }
  }
}

// ---------------------------------------------------------------------------
// WKV chunked scan on planar k/v/sr arrays. Direct fp32 recurrence (exponents
// bounded: |w*T|<=5, |k|~O(2), u~0). One wave per (b,chunk); lane owns 4
// channels -> bf16x4 loads (8 B/lane).
// ---------------------------------------------------------------------------
__global__ __launch_bounds__(256) void wkv_phase1(
    const __bf16* __restrict__ ka, const __bf16* __restrict__ va,
    const float* __restrict__ decay,
    float* __restrict__ Sloc, float* __restrict__ Zloc) {
  const int wave = threadIdx.x >> 6, lane = threadIdx.x & 63;
  const int gi = blockIdx.x * 4 + wave;          // 0..1023
  const int b = gi >> 7, chunk = gi & (NCHUNK - 1);
  const int c0 = lane * 4;
  const f32x4 w4 = *(const f32x4*)&decay[c0];
  f32x4 ew;
  #pragma unroll
  for (int r = 0; r < 4; r++) ew[r] = __expf(w4[r] * (1.0f / TDIM));
  f32x4 S = {0,0,0,0}, Z = {0,0,0,0};
  long long base = ((long long)b * TDIM + (long long)chunk * CHLEN) * 256 + c0;
  #pragma unroll 4
  for (int t = 0; t < CHLEN; t++) {
    const bf16x4 k4 = *(const bf16x4*)&ka[base + (long long)t * 256];
    const bf16x4 v4 = *(const bf16x4*)&va[base + (long long)t * 256];
    #pragma unroll
    for (int r = 0; r < 4; r++) {
      const float ek = __expf((float)k4[r]);
      S[r] = ew[r] * S[r] + ek * (float)v4[r];
      Z[r] = ew[r] * Z[r] + ek;
    }
  }
  const long long o = (long long)gi * 256 + c0;
  *(f32x4*)&Sloc[o] = S;
  *(f32x4*)&Zloc[o] = Z;
}

__global__ __launch_bounds__(256) void wkv_phase2(
    const float* __restrict__ Sloc, const float* __restrict__ Zloc,
    const float* __restrict__ decay,
    float* __restrict__ Sstart, float* __restrict__ Zstart) {
  const int idx = blockIdx.x * 256 + threadIdx.x;  // 0..2047
  const int c = idx & 255;
  const int b = idx >> 8;
  const float w = decay[c] * (1.0f / TDIM);
  const float ewL = __expf(w * (float)CHLEN);
  float S = 0.0f, Z = 0.0f;
  for (int j = 0; j < NCHUNK; j++) {
    const long long o = ((long long)b * NCHUNK + j) * 256 + c;
    Sstart[o] = S;
    Zstart[o] = Z;
    S = ewL * S + Sloc[o];
    Z = ewL * Z + Zloc[o];
  }
}

__global__ __launch_bounds__(256) void wkv_phase3(
    const __bf16* __restrict__ ka, const __bf16* __restrict__ va,
    const __bf16* __restrict__ ra,   // holds sigmoid(r)
    const float* __restrict__ decay, const float* __restrict__ first,
    const float* __restrict__ Sstart, const float* __restrict__ Zstart,
    __bf16* __restrict__ a2) {
  const int wave = threadIdx.x >> 6, lane = threadIdx.x & 63;
  const int gi = blockIdx.x * 4 + wave;
  const int b = gi >> 7, chunk = gi & (NCHUNK - 1);
  const int c0 = lane * 4;
  const f32x4 w4 = *(const f32x4*)&decay[c0];
  const f32x4 u4 = *(const f32x4*)&first[c0];
  f32x4 ew, eu;
  #pragma unroll
  for (int r = 0; r < 4; r++) {
    ew[r] = __expf(w4[r] * (1.0f / TDIM));
    eu[r] = __expf(u4[r] * (1.0f / TDIM));
  }
  const long long so = (long long)gi * 256 + c0;
  f32x4 S = *(const f32x4*)&Sstart[so];
  f32x4 Z = *(const f32x4*)&Zstart[so];
  long long base = ((long long)b * TDIM + (long long)chunk * CHLEN) * 256 + c0;
  #pragma unroll 2
  for (int t = 0; t < CHLEN; t++) {
    const long long p = base + (long long)t * 256;
    const bf16x4 k4 = *(const bf16x4*)&ka[p];
    const bf16x4 v4 = *(const bf16x4*)&va[p];
    const bf16x4 r4 = *(const bf16x4*)&ra[p];
    bf16x4 o;
    #pragma unroll
    for (int r = 0; r < 4; r++) {
      const float ek = __expf((float)k4[r]);
      const float E = eu[r] * ek;
      const float y = (S[r] + E * (float)v4[r]) / (Z[r] + E);
      o[r] = (__bf16)((float)r4[r] * y);
      S[r] = ew[r] * S[r] + ek * (float)v4[r];
      Z[r] = ew[r] * Z[r] + ek;
    }
    *(bf16x4*)&a2[p] = o;
  }
}

// ---------------------------------------------------------------------------
// Workspace layout (peak ~161.6 MB):
//   [0)      ka (bf16 16 MB)         [16M)  va          [32M)  ra (=sigmoid r)
//   [48M)    a2 (16 MB) -> reused as h2
//   [64M)    h  (16 MB) -> reused as g2
//   [80M)    x1h (bf16 16 MB)
//   [96M)    scan state S/Z (4 MB, dead before kk) then kk (bf16 64 MB)
//   [160M)   packed weights (~1.7 MB)
// ---------------------------------------------------------------------------
extern "C" void kernel_launch(void* const* d_in, const int* in_sizes, int n_in,
                              void* d_out, int out_size, void* d_ws, size_t ws_size,
                              hipStream_t stream) {
  const float* x     = (const float*)d_in[0];
  const float* Wk    = (const float*)d_in[1];
  const float* Wv    = (const float*)d_in[2];
  const float* Wr    = (const float*)d_in[3];
  const float* Wo    = (const float*)d_in[4];
  const float* Wkf   = (const float*)d_in[5];
  const float* Wvf   = (const float*)d_in[6];
  const float* Wrf   = (const float*)d_in[7];
  const float* g1    = (const float*)d_in[8];
  const float* b1    = (const float*)d_in[9];
  const float* g2    = (const float*)d_in[10];
  const float* b2    = (const float*)d_in[11];
  const float* decay = (const float*)d_in[12];
  const float* first = (const float*)d_in[13];
  float* out = (float*)d_out;
  char* ws = (char*)d_ws;

  __bf16* ka     = (__bf16*)(ws + 0);
  __bf16* va     = (__bf16*)(ws + 16777216LL);
  __bf16* ra     = (__bf16*)(ws + 33554432LL);
  __bf16* a2     = (__bf16*)(ws + 50331648LL);
  __bf16* h2     = (__bf16*)(ws + 50331648LL);      // reuses a2 (dead)
  __bf16* hbuf   = (__bf16*)(ws + 67108864LL);
  __bf16* g2buf  = (__bf16*)(ws + 67108864LL);      // reuses h (dead)
  __bf16* x1h    = (__bf16*)(ws + 83886080LL);
  float*  Sloc   = (float*)(ws + 100663296LL);      // dead before kk written
  float*  Zloc   = (float*)(ws + 101711872LL);
  float*  Sstart = (float*)(ws + 102760448LL);
  float*  Zstart = (float*)(ws + 103809024LL);
  __bf16* kk     = (__bf16*)(ws + 100663296LL);     // overwrites scan state
  __bf16* WkvrT  = (__bf16*)(ws + 167772160LL);
  __bf16* WoT    = (__bf16*)(ws + 168165376LL);
  __bf16* Wkfr   = (__bf16*)(ws + 168296448LL);
  __bf16* WvfT   = (__bf16*)(ws + 168951808LL);

  pack_weights<<<3328, 256, 0, stream>>>(Wk, Wv, Wr, Wo, Wkf, Wvf, Wrf,
                                         WkvrT, WoT, Wkfr, WvfT);

  // --- SpatialMix ---
  ln_kernel<float><<<NTOK / 4, 256, 0, stream>>>(x, g1, b1, hbuf);
  gemm5<256, 0><<<dim3(NTOK / 256, 12), 256, 0, stream>>>(
      hbuf, WkvrT, NTOK, 768, nullptr, ka, nullptr, nullptr, nullptr, nullptr);
  wkv_phase1<<<BDIM * NCHUNK / 4, 256, 0, stream>>>(ka, va, decay, Sloc, Zloc);
  wkv_phase2<<<BDIM, 256, 0, stream>>>(Sloc, Zloc, decay, Sstart, Zstart);
  wkv_phase3<<<BDIM * NCHUNK / 4, 256, 0, stream>>>(ka, va, ra, decay, first,
                                                    Sstart, Zstart, a2);
  gemm5<256, 1><<<dim3(NTOK / 256, 4), 256, 0, stream>>>(
      a2, WoT, NTOK, 256, nullptr, x1h, nullptr, x, nullptr, nullptr);

  // --- ChannelMix ---
  ln_kernel<__bf16><<<NTOK / 4, 256, 0, stream>>>(x1h, g2, b2, h2);
  gemm5<256, 2><<<dim3(NTOK / 256, 20), 256, 0, stream>>>(
      h2, Wkfr, NTOK, 1280, nullptr, kk, g2buf, nullptr, nullptr, nullptr);
  gemm5<1024, 3><<<dim3(NTOK / 256, 4), 256, 0, stream>>>(
      kk, WvfT, NTOK, 256, out, nullptr, nullptr, nullptr, x1h, g2buf);
}

// Round 8
// 278.626 us; speedup vs baseline: 1.1632x; 1.1632x over previous
//
#include <hip/hip_runtime.h>
#include <hip/hip_bf16.h>
#include <math.h>

// Problem constants
#define TDIM 4096
#define CDIM 256
#define BDIM 8
#define NTOK (BDIM * TDIM)   // 32768 rows
#define HIDDIM 1024
#define NCHUNK 128
#define CHLEN 32             // 4096 / 128

typedef float f32x4 __attribute__((ext_vector_type(4)));
typedef __bf16 bf16x8 __attribute__((ext_vector_type(8)));
typedef __bf16 bf16x4 __attribute__((ext_vector_type(4)));

// async global->LDS, 16 B/lane, lands at wave-uniform base + lane*16
#define GLDS16(gp, lp) __builtin_amdgcn_global_load_lds( \
    (const __attribute__((address_space(1))) void*)(gp), \
    (__attribute__((address_space(3))) void*)(lp), 16, 0, 0)

// s_waitcnt imm: vmcnt[3:0]|expcnt[6:4]|lgkmcnt[11:8]|vmcnt_hi[15:14]
#define WAITCNT_VM6 0x0F76
#define WAITCNT_VM4 0x0F74
#define WAITCNT_VM2 0x0F72
#define WAITCNT_VM0 0x0F70

__device__ __forceinline__ float sigm(float v) { return 1.0f / (1.0f + __expf(-v)); }

// ---------------------------------------------------------------------------
// Weight pack: fp32 [K,N] -> bf16 (or fp8) transposed [N,K].
//   WkvrT [768][256] bf16 = [Wk^T; Wv^T; Wr^T]
//   WoT   [256][256] bf16
//   Wkfr  [1280][256] bf16 = [Wkf^T; Wrf^T]
//   Wvf8  [256][1024] fp8 e4m3
// ---------------------------------------------------------------------------
__global__ __launch_bounds__(256) void pack_weights(
    const float* __restrict__ Wk, const float* __restrict__ Wv,
    const float* __restrict__ Wr, const float* __restrict__ Wo,
    const float* __restrict__ Wkf, const float* __restrict__ Wvf,
    const float* __restrict__ Wrf,
    __bf16* __restrict__ WkvrT, __bf16* __restrict__ WoT,
    __bf16* __restrict__ Wkfr, unsigned char* __restrict__ Wvf8) {
  long long j = (long long)blockIdx.x * 256 + threadIdx.x;
  if (j < 196608) {
    int n = (int)(j >> 8), k = (int)(j & 255);
    const float* src = (n < 256) ? Wk : (n < 512 ? Wv : Wr);
    WkvrT[j] = (__bf16)src[k * 256 + (n & 255)];
    return;
  }
  j -= 196608;
  if (j < 65536) { int n = (int)(j >> 8), k = (int)(j & 255);
    WoT[j] = (__bf16)Wo[k * 256 + n]; return; }
  j -= 65536;
  if (j < 327680) { int n = (int)(j >> 8), k = (int)(j & 255);
    Wkfr[j] = (__bf16)(n < 1024 ? Wkf[(long long)k * 1024 + n]
                                : Wrf[k * 256 + (n - 1024)]);
    return; }
  j -= 327680;
  if (j < 65536) {            // Wvf8: 4 bytes per thread
    const long long d = j * 4;
    const int n = (int)(d >> 10), k0 = (int)(d & 1023);
    int w = 0;
    w = __builtin_amdgcn_cvt_pk_fp8_f32(Wvf[(long long)k0 * 256 + n],
                                        Wvf[(long long)(k0 + 1) * 256 + n], w, false);
    w = __builtin_amdgcn_cvt_pk_fp8_f32(Wvf[(long long)(k0 + 2) * 256 + n],
                                        Wvf[(long long)(k0 + 3) * 256 + n], w, true);
    *(int*)&Wvf8[d] = w;
    return;
  }
}

// ---------------------------------------------------------------------------
// LayerNorm over C=256: one wave per row, 4 rows/block, float4 loads.
// ---------------------------------------------------------------------------
__global__ __launch_bounds__(256) void ln_kernel(
    const float* __restrict__ x, const float* __restrict__ gamma,
    const float* __restrict__ beta, __bf16* __restrict__ h) {
  const int wave = threadIdx.x >> 6, lane = threadIdx.x & 63;
  const long long row = (long long)blockIdx.x * 4 + wave;
  const long long base = row * CDIM + lane * 4;
  const f32x4 v = *(const f32x4*)&x[base];
  float s = v[0] + v[1] + v[2] + v[3];
  float s2 = v[0]*v[0] + v[1]*v[1] + v[2]*v[2] + v[3]*v[3];
  #pragma unroll
  for (int o = 1; o < 64; o <<= 1) { s += __shfl_xor(s, o); s2 += __shfl_xor(s2, o); }
  const float mean = s * (1.0f / CDIM);
  const float var = s2 * (1.0f / CDIM) - mean * mean;
  const float rstd = rsqrtf(var + 1e-5f);
  const f32x4 g4 = *(const f32x4*)&gamma[lane * 4];
  const f32x4 b4 = *(const f32x4*)&beta[lane * 4];
  bf16x4 o;
  #pragma unroll
  for (int r = 0; r < 4; r++) o[r] = (__bf16)((v[r] - mean) * rstd * g4[r] + b4[r]);
  *(bf16x4*)&h[base] = o;
}

// ---------------------------------------------------------------------------
// Pipelined bf16 MFMA GEMM (r5 structure: triple-buffered LDS, PD2, raw
// s_barrier + partial vmcnt).  C[M,N] = A[M,K] * Bt[N,K]^T, K=256.
// BM=128, BN in {128,256}; 4 waves as 2(m) x 2(n): wave tile 64 x BN/2.
// Accumulator TRANSPOSED (mfma(fb,fa)): lane (quad,mrow) reg r ->
//   row = mtile+mrow, col = ntile + quad*4 + r (4 consecutive cols/lane).
// EPI 0: planar kvr store, plane = blockIdx.y>>1 (0:k 1:v 2:sigmoid->r)
// EPI 1: (BN=256, N=256) FUSED residual+LN: t = srcF + acc; x1h=bf16(t);
//        h2 = LN(t)*g+b  (quad shuffle + cross-wave LDS reduction)
// EPI 2: y<8: kk8 = fp8(relu(acc)^2) [stride 1024]; y>=8: g2 = sigmoid [256]
// ---------------------------------------------------------------------------
template <int BN, int EPI>
__global__ __launch_bounds__(256, 2) void gemm3(
    const __bf16* __restrict__ A, const __bf16* __restrict__ Bt,
    int M, int N,
    __bf16* __restrict__ outH, __bf16* __restrict__ outH2,
    unsigned char* __restrict__ outC,
    const float* __restrict__ srcF,
    const float* __restrict__ gammaP, const float* __restrict__ betaP) {
  constexpr int K = 256;
  constexpr int WNT = BN / 32;        // n-tiles per wave
  constexpr int NBC = BN / 64;        // B staging calls per wave per iter
  __shared__ __bf16 sA[3][128 * 32];
  __shared__ __bf16 sB[3][BN * 32];
  __shared__ float redS[2][128], redQ[2][128];   // EPI1 only

  const int tid = threadIdx.x;
  const int wave = tid >> 6, lane = tid & 63;
  const int quad = lane >> 4, mrow = lane & 15;
  const long long bm = (long long)blockIdx.x * 128;
  const long long bn = (long long)blockIdx.y * BN;
  const int wm = (wave & 1) * 64, wn = (wave >> 1) * (BN / 2);

  const int lrow = lane >> 2;          // 0..15
  const int lk = (lane & 3) * 8;       // 0,8,16,24

  auto issue = [&](int g) {
    const int buf = g % 3;
    const long long k0 = (long long)g * 32;
    const int a0 = wave * 32;
    GLDS16(A + (bm + a0 + lrow) * (long long)K + k0 + lk, &sA[buf][a0 * 32]);
    GLDS16(A + (bm + a0 + 16 + lrow) * (long long)K + k0 + lk, &sA[buf][(a0 + 16) * 32]);
    #pragma unroll
    for (int bc = 0; bc < NBC; bc++) {
      const int r0 = wave * (BN / 4) + bc * 16;
      GLDS16(Bt + (bn + r0 + lrow) * (long long)K + k0 + lk, &sB[buf][r0 * 32]);
    }
  };

  f32x4 acc[4][WNT] = {};

  const int nit = K / 32;
  issue(0);
  issue(1);

  auto compute = [&](int i) {
    const int buf = i % 3;
    bf16x8 fa[4], fb[WNT];
    #pragma unroll
    for (int mt = 0; mt < 4; mt++)
      fa[mt] = *(const bf16x8*)&sA[buf][(wm + mt * 16 + mrow) * 32 + quad * 8];
    #pragma unroll
    for (int nt = 0; nt < WNT; nt++)
      fb[nt] = *(const bf16x8*)&sB[buf][(wn + nt * 16 + mrow) * 32 + quad * 8];
    #pragma unroll
    for (int mt = 0; mt < 4; mt++)
      #pragma unroll
      for (int nt = 0; nt < WNT; nt++)
        acc[mt][nt] = __builtin_amdgcn_mfma_f32_16x16x32_bf16(fb[nt], fa[mt], acc[mt][nt], 0, 0, 0);
  };

  #pragma unroll 1
  for (int i = 0; i < nit - 1; i++) {
    __builtin_amdgcn_s_waitcnt(BN == 256 ? WAITCNT_VM6 : WAITCNT_VM4);
    __builtin_amdgcn_s_barrier();
    if (i + 2 < nit) issue(i + 2);
    compute(i);
  }
  __builtin_amdgcn_s_waitcnt(WAITCNT_VM0);
  __builtin_amdgcn_s_barrier();
  compute(nit - 1);

  if (EPI == 1) {
    // ---- fused residual + LayerNorm (BN==256, N==256, grid.y==1) ----
    float sum[4] = {0, 0, 0, 0}, sq[4] = {0, 0, 0, 0};
    #pragma unroll
    for (int mt = 0; mt < 4; mt++) {
      #pragma unroll
      for (int nt = 0; nt < WNT; nt++) {
        const long long row = bm + wm + mt * 16 + mrow;
        const long long colb = wn + nt * 16 + quad * 4;
        acc[mt][nt] += *(const f32x4*)&srcF[row * 256 + colb];
        #pragma unroll
        for (int r = 0; r < 4; r++) {
          sum[mt] += acc[mt][nt][r];
          sq[mt] += acc[mt][nt][r] * acc[mt][nt][r];
        }
      }
    }
    #pragma unroll
    for (int mt = 0; mt < 4; mt++) {
      sum[mt] += __shfl_xor(sum[mt], 16); sq[mt] += __shfl_xor(sq[mt], 16);
      sum[mt] += __shfl_xor(sum[mt], 32); sq[mt] += __shfl_xor(sq[mt], 32);
    }
    const int wnh = wave >> 1;
    if (quad == 0) {
      #pragma unroll
      for (int mt = 0; mt < 4; mt++) {
        redS[wnh][wm + mt * 16 + mrow] = sum[mt];
        redQ[wnh][wm + mt * 16 + mrow] = sq[mt];
      }
    }
    __syncthreads();
    #pragma unroll
    for (int mt = 0; mt < 4; mt++) {
      const int rb = wm + mt * 16 + mrow;
      const float ts = redS[0][rb] + redS[1][rb];
      const float tq = redQ[0][rb] + redQ[1][rb];
      const float mean = ts * (1.0f / 256.0f);
      const float rstd = rsqrtf(tq * (1.0f / 256.0f) - mean * mean + 1e-5f);
      const long long row = bm + rb;
      #pragma unroll
      for (int nt = 0; nt < WNT; nt++) {
        const long long colb = wn + nt * 16 + quad * 4;
        const f32x4 g4 = *(const f32x4*)&gammaP[colb];
        const f32x4 b4 = *(const f32x4*)&betaP[colb];
        bf16x4 xo, ho;
        #pragma unroll
        for (int r = 0; r < 4; r++) {
          const float t = acc[mt][nt][r];
          xo[r] = (__bf16)t;
          ho[r] = (__bf16)((t - mean) * rstd * g4[r] + b4[r]);
        }
        *(bf16x4*)&outH[row * 256 + colb] = xo;    // x1h
        *(bf16x4*)&outH2[row * 256 + colb] = ho;   // h2
      }
    }
    return;
  }

  #pragma unroll
  for (int mt = 0; mt < 4; mt++) {
    #pragma unroll
    for (int nt = 0; nt < WNT; nt++) {
      const long long row = bm + wm + mt * 16 + mrow;
      const int cloc = wn + nt * 16 + quad * 4;
      const long long colb = bn + cloc;
      const f32x4 a = acc[mt][nt];
      if (EPI == 0) {
        const int plane = blockIdx.y >> 1;   // BN=128: 2 y-blocks per plane
        __bf16* o = outH + (long long)plane * ((long long)M * 256);
        const long long c2 = colb & 255;
        bf16x4 v;
        if (plane == 2) {
          #pragma unroll
          for (int r = 0; r < 4; r++) v[r] = (__bf16)sigm(a[r]);
        } else {
          #pragma unroll
          for (int r = 0; r < 4; r++) v[r] = (__bf16)a[r];
        }
        *(bf16x4*)&o[row * 256 + c2] = v;
      } else if (EPI == 2) {
        if (blockIdx.y < 8) {
          float t0 = a[0] > 0.0f ? a[0] : 0.0f;
          float t1 = a[1] > 0.0f ? a[1] : 0.0f;
          float t2 = a[2] > 0.0f ? a[2] : 0.0f;
          float t3 = a[3] > 0.0f ? a[3] : 0.0f;
          int w = 0;
          w = __builtin_amdgcn_cvt_pk_fp8_f32(t0 * t0, t1 * t1, w, false);
          w = __builtin_amdgcn_cvt_pk_fp8_f32(t2 * t2, t3 * t3, w, true);
          *(int*)&outC[row * 1024 + colb] = w;
        } else {
          bf16x4 v;
          #pragma unroll
          for (int r = 0; r < 4; r++) v[r] = (__bf16)sigm(a[r]);
          *(bf16x4*)&outH2[row * 256 + (colb - 1024)] = v;
        }
      }
    }
  }
}

// ---------------------------------------------------------------------------
// fp8 MFMA GEMM (K=1024): out[NTOK,256] = x1h + g2 * (kk8 @ Wvf8^T)
// A8 [NTOK][1024] fp8, B8 [256][1024] fp8. BM=128, BN=128, 4 waves 2x2,
// triple-buffered byte-LDS (PD2), 2 GLDS16/thread/iter (wait vmcnt<=2).
// LDS layout swizzled: byte addr = row*32 + ((kb>>4)^((row>>1)&1))*16+(kb&15)
// -> conflict-free 8-B fragment reads. Fragment: lane(quad,mrow) holds
// A[row=mrow][k=quad*8..+8] as i64 (same mapping as bf16 16x16x32).
// ---------------------------------------------------------------------------
__global__ __launch_bounds__(256, 4) void gemm6(
    const unsigned char* __restrict__ A8, const unsigned char* __restrict__ B8,
    float* __restrict__ outF, const __bf16* __restrict__ srcH,
    const __bf16* __restrict__ gate) {
  __shared__ unsigned char sA[3][128 * 32];
  __shared__ unsigned char sB[3][128 * 32];
  const int tid = threadIdx.x;
  const int wave = tid >> 6, lane = tid & 63;
  const int quad = lane >> 4, mrow = lane & 15;
  const long long bm = (long long)blockIdx.x * 128;
  const long long bn = (long long)blockIdx.y * 128;
  const int wm = (wave & 1) * 64, wn = (wave >> 1) * 64;
  const int srow = lane >> 1;                     // 0..31
  const int hs = (lane & 1) ^ ((lane >> 2) & 1);  // swizzled source half

  auto issue = [&](int g) {
    const int buf = g % 3;
    const long long k0 = (long long)g * 32;
    const int a0 = wave * 32;
    GLDS16(A8 + (bm + a0 + srow) * 1024LL + k0 + hs * 16, &sA[buf][a0 * 32]);
    GLDS16(B8 + (bn + a0 + srow) * 1024LL + k0 + hs * 16, &sB[buf][a0 * 32]);
  };

  f32x4 acc[4][4] = {};
  issue(0);
  issue(1);
  const int sw = (mrow >> 1) & 1;   // de-swizzle bit for fragment reads

  auto compute = [&](int i) {
    const int buf = i % 3;
    long long fa[4], fb[4];
    const int off = ((((quad >> 1) ^ sw) << 4) | ((quad & 1) << 3));
    #pragma unroll
    for (int mt = 0; mt < 4; mt++)
      fa[mt] = *(const long long*)&sA[buf][(wm + mt * 16 + mrow) * 32 + off];
    #pragma unroll
    for (int nt = 0; nt < 4; nt++)
      fb[nt] = *(const long long*)&sB[buf][(wn + nt * 16 + mrow) * 32 + off];
    #pragma unroll
    for (int mt = 0; mt < 4; mt++)
      #pragma unroll
      for (int nt = 0; nt < 4; nt++)
        acc[mt][nt] = __builtin_amdgcn_mfma_f32_16x16x32_fp8_fp8(fb[nt], fa[mt], acc[mt][nt], 0, 0, 0);
  };

  #pragma unroll 1
  for (int i = 0; i < 31; i++) {
    __builtin_amdgcn_s_waitcnt(WAITCNT_VM2);
    __builtin_amdgcn_s_barrier();
    if (i + 2 < 32) issue(i + 2);
    compute(i);
  }
  __builtin_amdgcn_s_waitcnt(WAITCNT_VM0);
  __builtin_amdgcn_s_barrier();
  compute(31);

  #pragma unroll
  for (int mt = 0; mt < 4; mt++) {
    #pragma unroll
    for (int nt = 0; nt < 4; nt++) {
      const long long row = bm + wm + mt * 16 + mrow;
      const long long colb = bn + wn + nt * 16 + quad * 4;
      const long long idx = row * 256 + colb;
      const f32x4 a = acc[mt][nt];
      const bf16x4 s4 = *(const bf16x4*)&srcH[idx];
      const bf16x4 g4 = *(const bf16x4*)&gate[idx];
      f32x4 v;
      #pragma unroll
      for (int r = 0; r < 4; r++) v[r] = (float)s4[r] + (float)g4[r] * a[r];
      *(f32x4*)&outF[idx] = v;
    }
  }
}

// ---------------------------------------------------------------------------
// WKV chunked scan on planar k/v/sr arrays (r5, unchanged). Direct fp32
// recurrence; exponents bounded.
// ---------------------------------------------------------------------------
__global__ __launch_bounds__(256) void wkv_phase1(
    const __bf16* __restrict__ ka, const __bf16* __restrict__ va,
    const float* __restrict__ decay,
    float* __restrict__ Sloc, float* __restrict__ Zloc) {
  const int wave = threadIdx.x >> 6, lane = threadIdx.x & 63;
  const int gi = blockIdx.x * 4 + wave;          // 0..1023
  const int b = gi >> 7, chunk = gi & (NCHUNK - 1);
  const int c0 = lane * 4;
  const f32x4 w4 = *(const f32x4*)&decay[c0];
  f32x4 ew;
  #pragma unroll
  for (int r = 0; r < 4; r++) ew[r] = __expf(w4[r] * (1.0f / TDIM));
  f32x4 S = {0,0,0,0}, Z = {0,0,0,0};
  long long base = ((long long)b * TDIM + (long long)chunk * CHLEN) * 256 + c0;
  #pragma unroll 4
  for (int t = 0; t < CHLEN; t++) {
    const bf16x4 k4 = *(const bf16x4*)&ka[base + (long long)t * 256];
    const bf16x4 v4 = *(const bf16x4*)&va[base + (long long)t * 256];
    #pragma unroll
    for (int r = 0; r < 4; r++) {
      const float ek = __expf((float)k4[r]);
      S[r] = ew[r] * S[r] + ek * (float)v4[r];
      Z[r] = ew[r] * Z[r] + ek;
    }
  }
  const long long o = (long long)gi * 256 + c0;
  *(f32x4*)&Sloc[o] = S;
  *(f32x4*)&Zloc[o] = Z;
}

__global__ __launch_bounds__(256) void wkv_phase2(
    const float* __restrict__ Sloc, const float* __restrict__ Zloc,
    const float* __restrict__ decay,
    float* __restrict__ Sstart, float* __restrict__ Zstart) {
  const int idx = blockIdx.x * 256 + threadIdx.x;  // 0..2047
  const int c = idx & 255;
  const int b = idx >> 8;
  const float w = decay[c] * (1.0f / TDIM);
  const float ewL = __expf(w * (float)CHLEN);
  float S = 0.0f, Z = 0.0f;
  for (int j = 0; j < NCHUNK; j++) {
    const long long o = ((long long)b * NCHUNK + j) * 256 + c;
    Sstart[o] = S;
    Zstart[o] = Z;
    S = ewL * S + Sloc[o];
    Z = ewL * Z + Zloc[o];
  }
}

__global__ __launch_bounds__(256) void wkv_phase3(
    const __bf16* __restrict__ ka, const __bf16* __restrict__ va,
    const __bf16* __restrict__ ra,   // holds sigmoid(r)
    const float* __restrict__ decay, const float* __restrict__ first,
    const float* __restrict__ Sstart, const float* __restrict__ Zstart,
    __bf16* __restrict__ a2) {
  const int wave = threadIdx.x >> 6, lane = threadIdx.x & 63;
  const int gi = blockIdx.x * 4 + wave;
  const int b = gi >> 7, chunk = gi & (NCHUNK - 1);
  const int c0 = lane * 4;
  const f32x4 w4 = *(const f32x4*)&decay[c0];
  const f32x4 u4 = *(const f32x4*)&first[c0];
  f32x4 ew, eu;
  #pragma unroll
  for (int r = 0; r < 4; r++) {
    ew[r] = __expf(w4[r] * (1.0f / TDIM));
    eu[r] = __expf(u4[r] * (1.0f / TDIM));
  }
  const long long so = (long long)gi * 256 + c0;
  f32x4 S = *(const f32x4*)&Sstart[so];
  f32x4 Z = *(const f32x4*)&Zstart[so];
  long long base = ((long long)b * TDIM + (long long)chunk * CHLEN) * 256 + c0;
  #pragma unroll 2
  for (int t = 0; t < CHLEN; t++) {
    const long long p = base + (long long)t * 256;
    const bf16x4 k4 = *(const bf16x4*)&ka[p];
    const bf16x4 v4 = *(const bf16x4*)&va[p];
    const bf16x4 r4 = *(const bf16x4*)&ra[p];
    bf16x4 o;
    #pragma unroll
    for (int r = 0; r < 4; r++) {
      const float ek = __expf((float)k4[r]);
      const float E = eu[r] * ek;
      const float y = (S[r] + E * (float)v4[r]) / (Z[r] + E);
      o[r] = (__bf16)((float)r4[r] * y);
      S[r] = ew[r] * S[r] + ek * (float)v4[r];
      Z[r] = ew[r] * Z[r] + ek;
    }
    *(bf16x4*)&a2[p] = o;
  }
}

// ---------------------------------------------------------------------------
// Workspace layout (peak ~162 MB):
//   [0)    ka 16M | [16M) va | [32M) ra (=sigmoid r)
//   [48M)  a2 16M -> reused as g2buf after EPI1
//   [64M)  h 16M  -> reused as h2 (written by fused EPI1)
//   [80M)  x1h 16M
//   [96M)  scan state S/Z 4M (dead before kk8) then kk8 (fp8 33.5M)
//   [160M) packed weights (~1.5 MB)
// ---------------------------------------------------------------------------
extern "C" void kernel_launch(void* const* d_in, const int* in_sizes, int n_in,
                              void* d_out, int out_size, void* d_ws, size_t ws_size,
                              hipStream_t stream) {
  const float* x     = (const float*)d_in[0];
  const float* Wk    = (const float*)d_in[1];
  const float* Wv    = (const float*)d_in[2];
  const float* Wr    = (const float*)d_in[3];
  const float* Wo    = (const float*)d_in[4];
  const float* Wkf   = (const float*)d_in[5];
  const float* Wvf   = (const float*)d_in[6];
  const float* Wrf   = (const float*)d_in[7];
  const float* g1    = (const float*)d_in[8];
  const float* b1    = (const float*)d_in[9];
  const float* g2    = (const float*)d_in[10];
  const float* b2    = (const float*)d_in[11];
  const float* decay = (const float*)d_in[12];
  const float* first = (const float*)d_in[13];
  float* out = (float*)d_out;
  char* ws = (char*)d_ws;

  __bf16* ka     = (__bf16*)(ws + 0);
  __bf16* va     = (__bf16*)(ws + 16777216LL);
  __bf16* ra     = (__bf16*)(ws + 33554432LL);
  __bf16* a2     = (__bf16*)(ws + 50331648LL);
  __bf16* g2buf  = (__bf16*)(ws + 50331648LL);      // reuses a2 (dead after EPI1)
  __bf16* hbuf   = (__bf16*)(ws + 67108864LL);
  __bf16* h2     = (__bf16*)(ws + 67108864LL);      // reuses hbuf (dead after EPI0)
  __bf16* x1h    = (__bf16*)(ws + 83886080LL);
  float*  Sloc   = (float*)(ws + 100663296LL);      // dead before kk8 written
  float*  Zloc   = (float*)(ws + 101711872LL);
  float*  Sstart = (float*)(ws + 102760448LL);
  float*  Zstart = (float*)(ws + 103809024LL);
  unsigned char* kk8 = (unsigned char*)(ws + 100663296LL);   // overwrites scan state
  __bf16* WkvrT  = (__bf16*)(ws + 167772160LL);
  __bf16* WoT    = (__bf16*)(ws + 168165376LL);
  __bf16* Wkfr   = (__bf16*)(ws + 168296448LL);
  unsigned char* Wvf8 = (unsigned char*)(ws + 168951808LL);

  pack_weights<<<2560, 256, 0, stream>>>(Wk, Wv, Wr, Wo, Wkf, Wvf, Wrf,
                                         WkvrT, WoT, Wkfr, Wvf8);

  // --- SpatialMix ---
  ln_kernel<<<NTOK / 4, 256, 0, stream>>>(x, g1, b1, hbuf);
  gemm3<128, 0><<<dim3(NTOK / 128, 6), 256, 0, stream>>>(
      hbuf, WkvrT, NTOK, 768, ka, nullptr, nullptr, nullptr, nullptr, nullptr);
  wkv_phase1<<<BDIM * NCHUNK / 4, 256, 0, stream>>>(ka, va, decay, Sloc, Zloc);
  wkv_phase2<<<BDIM, 256, 0, stream>>>(Sloc, Zloc, decay, Sstart, Zstart);
  wkv_phase3<<<BDIM * NCHUNK / 4, 256, 0, stream>>>(ka, va, ra, decay, first,
                                                    Sstart, Zstart, a2);
  // x1 = x + a2@Wo, fused with LN2: writes x1h (bf16) and h2 = LN(x1)
  gemm3<256, 1><<<dim3(NTOK / 128, 1), 256, 0, stream>>>(
      a2, WoT, NTOK, 256, x1h, h2, nullptr, x, g2, b2);

  // --- ChannelMix ---
  gemm3<128, 2><<<dim3(NTOK / 128, 10), 256, 0, stream>>>(
      h2, Wkfr, NTOK, 1280, nullptr, g2buf, kk8, nullptr, nullptr, nullptr);
  gemm6<<<dim3(NTOK / 128, 2), 256, 0, stream>>>(
      kk8, Wvf8, out, x1h, g2buf);
}